// Round 3
// baseline (526.732 us; speedup 1.0000x reference)
//
#include <hip/hip_runtime.h>

// BlockAxialDown: pool2x2 -> axial attn (H)+(W) -> relu -> concat -> 1x1 conv
// -> relu -> batch-stat BN -> NCHW.  B=8 C=128 H2=W2=128 E=256, heads=2 dh=64.
//
// ws arrays (bf16 activations):
//   xp [b][h][w][c]  pooled x
//   ah [b][w][h][c]  H-attn out (+bias)          (w-major: coalesced for attn0)
//   aw [b][h][w][c]  W-attn out (+bias)
//   yb [b][e][h][w]  pre-BN conv out (bf16)
// conv stages relu(ah+aw) | xp, writes yb + 16-way-spread channel stats.
// bn reads yb, writes fp32 NCHW out.

typedef short v8s __attribute__((ext_vector_type(8)));
typedef short v4s __attribute__((ext_vector_type(4)));
typedef float v4f __attribute__((ext_vector_type(4)));

#define LSA 136   // attn LDS row stride (bf16): frag reads land uniform on banks
#define LSC 264   // conv LDS row stride

static __device__ __forceinline__ short f2bf(float f){
  unsigned u = __builtin_bit_cast(unsigned, f);
  u = (u + 0x7FFFu + ((u >> 16) & 1u)) >> 16;   // RNE
  return (short)u;
}
static __device__ __forceinline__ float bf2f(short s){
  unsigned u = ((unsigned)(unsigned short)s) << 16;
  return __builtin_bit_cast(float, u);
}

// ---------------- prep: transpose weights to bf16 [out][in]; zero stats ----
__global__ void prep_kernel(const float* __restrict__ Wq_h, const float* __restrict__ Wkv_h,
                            const float* __restrict__ Wout_h, const float* __restrict__ Wq_w,
                            const float* __restrict__ Wkv_w, const float* __restrict__ Wout_w,
                            const float* __restrict__ conv_w, short* __restrict__ wt,
                            float* __restrict__ stats){
  int idx = blockIdx.x * 256 + threadIdx.x;   // 768*256 = 196608 exactly
  if (idx < 8192) stats[idx] = 0.0f;          // 16 copies x 512
  const float* src; int K, O, base;
  if      (idx <  16384){ base = 0;      K=128; O=128; src=Wq_h;  }
  else if (idx <  49152){ base = 16384;  K=128; O=256; src=Wkv_h; }
  else if (idx <  65536){ base = 49152;  K=128; O=128; src=Wout_h;}
  else if (idx <  81920){ base = 65536;  K=128; O=128; src=Wq_w;  }
  else if (idx < 114688){ base = 81920;  K=128; O=256; src=Wkv_w; }
  else if (idx < 131072){ base = 114688; K=128; O=128; src=Wout_w;}
  else                  { base = 131072; K=256; O=256; src=conv_w;}
  int local = idx - base;
  int o = local / K, i = local - o * K;
  wt[idx] = f2bf(src[i * O + o]);   // dst[o][i] = src[i][o]
}

// ---------------- maxpool 2x2 -> bf16 xp[b][h][w][c] ----------------------
__global__ void pool_kernel(const float* __restrict__ x, short* __restrict__ xp){
  int bx = blockIdx.x;              // (b*128+i)*2 + jh
  int jh = bx & 1, row = bx >> 1;
  int b = row >> 7, i = row & 127;
  int tid = (int)threadIdx.x;
  int j = jh * 64 + (tid & 63);     // lanes = consecutive j -> coalesced reads
  int cq = tid >> 6;
  for (int rep = 0; rep < 8; ++rep){
    int c0 = (rep * 4 + cq) * 4;
    v4s outv;
    for (int cc = 0; cc < 4; ++cc){
      int c = c0 + cc;
      const float* p0 = x + (((b*128 + c)*256 + 2*i)*256 + 2*j);
      float2 a  = *(const float2*)p0;
      float2 bb = *(const float2*)(p0 + 256);
      outv[cc] = f2bf(fmaxf(fmaxf(a.x, a.y), fmaxf(bb.x, bb.y)));
    }
    *(v4s*)(xp + ((row*128 + j)*128 + c0)) = outv;
  }
}

// ---------------- fused axial attention, one (b,s) per 512-thr block ------
// 8 waves, wave = 16-token band, both heads. Single LDS buffer multiplexed
// q -> k -> P -> v^T -> O -> Z; q/P/O phases are wave-local (band rows only).
// DIR=0: H-attn (s=w, t=h, weights _h) -> ah.  DIR=1: W-attn -> aw.
template<int DIR>
__global__ __launch_bounds__(512, 4)
void attn_kernel(const short* __restrict__ xp, const short* __restrict__ wt,
                 const float* __restrict__ bout, short* __restrict__ ao){
  __shared__ short bufB[128*LSA];   // 34,816 B

  const int bx = blockIdx.x;
  const int b = bx >> 7, s = bx & 127;
  const int tid = (int)threadIdx.x;
  const int w = tid >> 6;
  const int lane = tid & 63;
  const int l15 = lane & 15, l4 = lane >> 4;

  const short* WqT   = wt + (DIR == 0 ? 0     : 65536);
  const short* WkT   = wt + (DIR == 0 ? 16384 : 81920);
  const short* WvT   = WkT + 16384;
  const short* WoutT = wt + (DIR == 0 ? 49152 : 114688);

  // ---- A-fragments of x straight from global (64B-line granular) ----
  const int trow = 16*w + l15;
  int xbase = (DIR == 0) ? (((b*128 + trow)*128 + s)*128)
                         : (((b*128 + s)*128 + trow)*128);
  v8s av[4];
  #pragma unroll
  for (int kk = 0; kk < 4; ++kk)
    av[kk] = *(const v8s*)(xp + xbase + kk*32 + l4*8);

  // ---- q = x @ Wq -> bufB band rows (wave-local) ----
  #pragma unroll
  for (int tc = 0; tc < 8; ++tc){
    v4f d = {0.f,0.f,0.f,0.f};
    #pragma unroll
    for (int kk = 0; kk < 4; ++kk){
      v8s bf = *(const v8s*)(WqT + (tc*16 + l15)*128 + kk*32 + l4*8);
      d = __builtin_amdgcn_mfma_f32_16x16x32_bf16(av[kk], bf, d, 0, 0, 0);
    }
    #pragma unroll
    for (int r = 0; r < 4; ++r)
      bufB[(16*w + 4*l4 + r)*LSA + 16*tc + l15] = f2bf(d[r]);
  }
  v8s bq[2][2];                     // wave-local read-back (B-frags of Q^T)
  #pragma unroll
  for (int h = 0; h < 2; ++h)
    #pragma unroll
    for (int kk = 0; kk < 2; ++kk)
      bq[h][kk] = *(const v8s*)(&bufB[(16*w + l15)*LSA + h*64 + kk*32 + l4*8]);

  // ---- k = x @ Wkv[:,:128] -> bufB band rows (wave-local WAR) ----
  #pragma unroll
  for (int tc = 0; tc < 8; ++tc){
    v4f d = {0.f,0.f,0.f,0.f};
    #pragma unroll
    for (int kk = 0; kk < 4; ++kk){
      v8s bf = *(const v8s*)(WkT + (tc*16 + l15)*128 + kk*32 + l4*8);
      d = __builtin_amdgcn_mfma_f32_16x16x32_bf16(av[kk], bf, d, 0, 0, 0);
    }
    #pragma unroll
    for (int r = 0; r < 4; ++r)
      bufB[(16*w + 4*l4 + r)*LSA + 16*tc + l15] = f2bf(d[r]);
  }
  __syncthreads();                  // b1: k visible to all waves

  // ---- S^T = K.Q^T per head + softmax; keep P packed in regs ----
  v4s pk[2][8];
  #pragma unroll
  for (int h = 0; h < 2; ++h){
    v4f st[8];
    #pragma unroll
    for (int jt = 0; jt < 8; ++jt){
      v4f d = {0.f,0.f,0.f,0.f};
      #pragma unroll
      for (int kk = 0; kk < 2; ++kk){
        v8s ak = *(const v8s*)(&bufB[(16*jt + l15)*LSA + h*64 + kk*32 + l4*8]);
        d = __builtin_amdgcn_mfma_f32_16x16x32_bf16(ak, bq[h][kk], d, 0, 0, 0);
      }
      st[jt] = d;
    }
    float mx = -1e30f;
    #pragma unroll
    for (int jt = 0; jt < 8; ++jt)
      #pragma unroll
      for (int r = 0; r < 4; ++r) mx = fmaxf(mx, st[jt][r]);
    mx = fmaxf(mx, __shfl_xor(mx, 16));
    mx = fmaxf(mx, __shfl_xor(mx, 32));
    float sm = 0.f;
    #pragma unroll
    for (int jt = 0; jt < 8; ++jt)
      #pragma unroll
      for (int r = 0; r < 4; ++r){
        float e = __expf((st[jt][r] - mx) * 0.125f);   // * dh^-0.5
        st[jt][r] = e; sm += e;
      }
    sm += __shfl_xor(sm, 16);
    sm += __shfl_xor(sm, 32);
    float inv = 1.0f / sm;
    #pragma unroll
    for (int jt = 0; jt < 8; ++jt)
      #pragma unroll
      for (int r = 0; r < 4; ++r) pk[h][jt][r] = f2bf(st[jt][r] * inv);
  }
  __syncthreads();                  // b2: all k reads done

  // ---- P -> bufB band rows, re-read as A-frags (all wave-local) ----
  v8s pa[2][4];
  #pragma unroll
  for (int h = 0; h < 2; ++h){
    #pragma unroll
    for (int jt = 0; jt < 8; ++jt)
      *(v4s*)(&bufB[(16*w + l15)*LSA + 16*jt + 4*l4]) = pk[h][jt];
    #pragma unroll
    for (int kk = 0; kk < 4; ++kk)
      pa[h][kk] = *(const v8s*)(&bufB[(16*w + l15)*LSA + kk*32 + l4*8]);
  }
  __syncthreads();                  // b3: P phase done, bufB free for v^T

  // ---- v^T = (x @ Wkv[:,128:])^T -> bufB [chan][t] ----
  #pragma unroll
  for (int tc = 0; tc < 8; ++tc){
    v4f d = {0.f,0.f,0.f,0.f};
    #pragma unroll
    for (int kk = 0; kk < 4; ++kk){
      v8s bf = *(const v8s*)(WvT + (tc*16 + l15)*128 + kk*32 + l4*8);
      d = __builtin_amdgcn_mfma_f32_16x16x32_bf16(av[kk], bf, d, 0, 0, 0);
    }
    v4s pkv;
    #pragma unroll
    for (int r = 0; r < 4; ++r) pkv[r] = f2bf(d[r]);
    *(v4s*)(&bufB[(16*tc + l15)*LSA + 16*w + 4*l4]) = pkv;
  }
  __syncthreads();                  // b4: v^T visible

  // ---- O^T = V^T . P^T (A from LDS, B from regs) ----
  v4f ot[2][4];
  #pragma unroll
  for (int h = 0; h < 2; ++h)
    #pragma unroll
    for (int tc = 0; tc < 4; ++tc){
      v4f d = {0.f,0.f,0.f,0.f};
      #pragma unroll
      for (int kk = 0; kk < 4; ++kk){
        v8s vf = *(const v8s*)(&bufB[(64*h + 16*tc + l15)*LSA + kk*32 + l4*8]);
        d = __builtin_amdgcn_mfma_f32_16x16x32_bf16(vf, pa[h][kk], d, 0, 0, 0);
      }
      ot[h][tc] = d;
    }
  __syncthreads();                  // b5: all v^T reads done

  // ---- O -> bufB [i][d] band rows; out-proj; Z -> bufB [t][oc] ----
  #pragma unroll
  for (int h = 0; h < 2; ++h)
    #pragma unroll
    for (int tc = 0; tc < 4; ++tc){
      v4s pko;
      #pragma unroll
      for (int r = 0; r < 4; ++r) pko[r] = f2bf(ot[h][tc][r]);
      *(v4s*)(&bufB[(16*w + l15)*LSA + 64*h + 16*tc + 4*l4]) = pko;
    }
  v8s ob[4];
  #pragma unroll
  for (int kk = 0; kk < 4; ++kk)
    ob[kk] = *(const v8s*)(&bufB[(16*w + l15)*LSA + kk*32 + l4*8]);
  #pragma unroll
  for (int tc = 0; tc < 8; ++tc){
    v4f d = {0.f,0.f,0.f,0.f};
    #pragma unroll
    for (int kk = 0; kk < 4; ++kk){
      v8s awf = *(const v8s*)(WoutT + (tc*16 + l15)*128 + kk*32 + l4*8);
      d = __builtin_amdgcn_mfma_f32_16x16x32_bf16(awf, ob[kk], d, 0, 0, 0);
    }
    v4f bias = *(const v4f*)(bout + 16*tc + 4*l4);
    v4s z;
    #pragma unroll
    for (int r = 0; r < 4; ++r) z[r] = f2bf(d[r] + bias[r]);
    *(v4s*)(&bufB[(16*w + l15)*LSA + 16*tc + 4*l4]) = z;
  }
  __syncthreads();                  // b6: Z tile complete

  // ---- coalesced store of [128 t][128 oc] tile ----
  int obase = ((b*128 + s)*128)*128;
  #pragma unroll
  for (int r = 0; r < 4; ++r){
    int idx = (r*512 + tid) * 8;
    int t = idx >> 7, c = idx & 127;
    *(v8s*)(ao + obase + t*128 + c) = *(const v8s*)(&bufB[t*LSA + c]);
  }
}

// ---------------- concat + 1x1 conv + relu + bf16 y + stats ---------------
__global__ __launch_bounds__(512, 4)
void conv_kernel(const short* __restrict__ ah, const short* __restrict__ aw,
                 const short* __restrict__ xp, const short* __restrict__ wt,
                 short* __restrict__ yb, float* __restrict__ stats){
  __shared__ short cats[128*LSC];   // staged [t][256]; reused as y [256][132]
  __shared__ float lsum[256];
  __shared__ float lsq[256];
  const short* convT = wt + 131072; // [e][f] bf16
  int bx = blockIdx.x;              // b*128 + ii (image h-row; tokens j = w)
  int b = bx >> 7, ii = bx & 127;
  int tid = (int)threadIdx.x;
  int wv = tid >> 6, lane = tid & 63, l15 = lane & 15, l4 = lane >> 4;
  if (tid < 256){ lsum[tid] = 0.f; lsq[tid] = 0.f; }
  for (int r = 0; r < 4; ++r){
    int idx = (r*512 + tid) * 8;
    int t = idx >> 7, c = idx & 127;
    v8s hv = *(const v8s*)(ah + ((b*128 + t)*128 + ii)*128 + c);
    v8s wv_ = *(const v8s*)(aw + ((b*128 + ii)*128 + t)*128 + c);
    v8s o;
    #pragma unroll
    for (int k = 0; k < 8; ++k)
      o[k] = f2bf(fmaxf(bf2f(hv[k]) + bf2f(wv_[k]), 0.f));
    *(v8s*)(&cats[t*LSC + c]) = o;
    *(v8s*)(&cats[t*LSC + 128 + c]) =
        *(const v8s*)(xp + ((b*128 + ii)*128 + t)*128 + c);
  }
  __syncthreads();
  v8s af[8];
  #pragma unroll
  for (int kk = 0; kk < 8; ++kk)
    af[kk] = *(const v8s*)(&cats[(16*wv + l15)*LSC + kk*32 + l4*8]);
  __syncthreads();                  // all af loaded before y overwrites
  for (int tc = 0; tc < 16; ++tc){
    v4f d = {0.f,0.f,0.f,0.f};
    #pragma unroll
    for (int kk = 0; kk < 8; ++kk){
      v8s bf = *(const v8s*)(convT + (tc*16 + l15)*256 + kk*32 + l4*8);
      d = __builtin_amdgcn_mfma_f32_16x16x32_bf16(af[kk], bf, d, 0, 0, 0);
    }
    int e  = 16*tc + l15;
    int j0 = 16*wv + 4*l4;
    v4s yp;
    float s1 = 0.f, s2 = 0.f;
    #pragma unroll
    for (int r = 0; r < 4; ++r){
      float y = fmaxf(d[r], 0.f);
      yp[r] = f2bf(y);
      s1 += y; s2 += y*y;
    }
    *(v4s*)(&cats[e*132 + j0]) = yp;
    s1 += __shfl_xor(s1, 16); s1 += __shfl_xor(s1, 32);
    s2 += __shfl_xor(s2, 16); s2 += __shfl_xor(s2, 32);
    if (l4 == 0){
      atomicAdd(&lsum[e], s1);
      atomicAdd(&lsq[e], s2);
    }
  }
  __syncthreads();
  for (int r = 0; r < 8; ++r){      // coalesced bf16 y store [b][e][ii][j]
    int idx = (r*512 + tid) * 8;
    int e = idx >> 7, j = idx & 127;
    *(v8s*)(yb + ((b*256 + e)*128 + ii)*128 + j) = *(const v8s*)(&cats[e*132 + j]);
  }
  if (tid < 256){
    int c = bx & 15;                // 16-way spread
    atomicAdd(&stats[c*512 + tid],       lsum[tid]);
    atomicAdd(&stats[c*512 + 256 + tid], lsq[tid]);
  }
}

// ---------------- BN: bf16 y -> fp32 out, block = one (b,e) plane ---------
__global__ void bn_kernel(const short* __restrict__ yb, float* __restrict__ out,
                          const float* __restrict__ stats,
                          const float* __restrict__ gamma, const float* __restrict__ beta){
  const float invn = 1.0f / 131072.0f;
  int bx = blockIdx.x;              // b*256 + e
  int e = bx & 255;
  float s1 = 0.f, s2 = 0.f;
  #pragma unroll
  for (int c = 0; c < 16; ++c){
    s1 += stats[c*512 + e];
    s2 += stats[c*512 + 256 + e];
  }
  float m   = s1 * invn;
  float var = s2 * invn - m * m;
  float sc  = gamma[e] * rsqrtf(var + 1e-5f);
  float sh  = beta[e] - m * sc;
  int base = bx * 16384;
  int tid = (int)threadIdx.x;       // 256
  for (int rep = 0; rep < 8; ++rep){
    int idx = base + (rep*256 + tid)*8;
    v8s yv = *(const v8s*)(yb + idx);
    v4f o1, o2;
    #pragma unroll
    for (int r = 0; r < 4; ++r){
      o1[r] = bf2f(yv[r])   * sc + sh;
      o2[r] = bf2f(yv[4+r]) * sc + sh;
    }
    *(v4f*)(out + idx)     = o1;
    *(v4f*)(out + idx + 4) = o2;
  }
}

extern "C" void kernel_launch(void* const* d_in, const int* in_sizes, int n_in,
                              void* d_out, int out_size, void* d_ws, size_t ws_size,
                              hipStream_t stream){
  const float* x      = (const float*)d_in[0];
  const float* Wq_h   = (const float*)d_in[1];
  const float* Wkv_h  = (const float*)d_in[2];
  const float* Wout_h = (const float*)d_in[3];
  const float* bout_h = (const float*)d_in[4];
  const float* Wq_w   = (const float*)d_in[5];
  const float* Wkv_w  = (const float*)d_in[6];
  const float* Wout_w = (const float*)d_in[7];
  const float* bout_w = (const float*)d_in[8];
  const float* conv_w = (const float*)d_in[9];
  const float* gamma  = (const float*)d_in[10];
  const float* beta   = (const float*)d_in[11];
  float* out = (float*)d_out;

  char* ws = (char*)d_ws;
  short* xp    = (short*)(ws);               // 33,554,432 B
  short* ah    = (short*)(ws +  33554432);   // 33,554,432 B  [b][w][h][c]
  short* aw    = (short*)(ws +  67108864);   // 33,554,432 B  [b][h][w][c]
  short* yb    = (short*)(ws + 100663296);   // 67,108,864 B  [b][e][h][w]
  short* wt    = (short*)(ws + 167772160);   //    393,216 B
  float* stats = (float*)(ws + 168165376);   //     32,768 B

  prep_kernel<<<768, 256, 0, stream>>>(Wq_h, Wkv_h, Wout_h, Wq_w, Wkv_w, Wout_w,
                                       conv_w, wt, stats);
  pool_kernel<<<2048, 256, 0, stream>>>(x, xp);
  attn_kernel<0><<<1024, 512, 0, stream>>>(xp, wt, bout_h, ah);
  attn_kernel<1><<<1024, 512, 0, stream>>>(xp, wt, bout_w, aw);
  conv_kernel<<<1024, 512, 0, stream>>>(ah, aw, xp, wt, yb, stats);
  bn_kernel<<<2048, 256, 0, stream>>>(yb, out, stats, gamma, beta);
}

// Round 4
// 345.125 us; speedup vs baseline: 1.5262x; 1.5262x over previous
//
#include <hip/hip_runtime.h>

// BlockAxialDown: pool2x2 -> axial attn (H)+(W) -> relu -> concat -> 1x1 conv
// -> relu -> batch-stat BN -> NCHW.  B=8 C=128 H2=W2=128 E=256, heads=2 dh=64.
//
// ws (bf16):
//   xp_hw [b][h][w][c], xp_wh [b][w][h][c]  pooled x, both layouts
//   ah [b][w][h][c]  H-attn out (+bias)
//   aw [b][h][w][c]  W-attn out (+bias)
//   yb [b][e][h][w]  pre-BN conv out
// attn (merged dirs): weights staged via LDS, x A-frags from contiguous tile.

typedef short v8s __attribute__((ext_vector_type(8)));
typedef short v4s __attribute__((ext_vector_type(4)));
typedef float v4f __attribute__((ext_vector_type(4)));

#define LSA 136   // attn LDS row stride (bf16)
#define LSC 264   // conv LDS row stride
#define LSP 130   // pool LDS row stride

static __device__ __forceinline__ short f2bf(float f){
  unsigned u = __builtin_bit_cast(unsigned, f);
  u = (u + 0x7FFFu + ((u >> 16) & 1u)) >> 16;   // RNE
  return (short)u;
}
static __device__ __forceinline__ float bf2f(short s){
  unsigned u = ((unsigned)(unsigned short)s) << 16;
  return __builtin_bit_cast(float, u);
}

// ---------------- prep: transpose weights to bf16 [out][in]; zero stats ----
__global__ void prep_kernel(const float* __restrict__ Wq_h, const float* __restrict__ Wkv_h,
                            const float* __restrict__ Wout_h, const float* __restrict__ Wq_w,
                            const float* __restrict__ Wkv_w, const float* __restrict__ Wout_w,
                            const float* __restrict__ conv_w, short* __restrict__ wt,
                            float* __restrict__ stats){
  int idx = blockIdx.x * 256 + threadIdx.x;   // 768*256 = 196608 exactly
  if (idx < 8192) stats[idx] = 0.0f;          // 16 copies x 512
  const float* src; int K, O, base;
  if      (idx <  16384){ base = 0;      K=128; O=128; src=Wq_h;  }
  else if (idx <  49152){ base = 16384;  K=128; O=256; src=Wkv_h; }
  else if (idx <  65536){ base = 49152;  K=128; O=128; src=Wout_h;}
  else if (idx <  81920){ base = 65536;  K=128; O=128; src=Wq_w;  }
  else if (idx < 114688){ base = 81920;  K=128; O=256; src=Wkv_w; }
  else if (idx < 131072){ base = 114688; K=128; O=128; src=Wout_w;}
  else                  { base = 131072; K=256; O=256; src=conv_w;}
  int local = idx - base;
  int o = local / K, i = local - o * K;
  wt[idx] = f2bf(src[i * O + o]);   // dst[o][i] = src[i][o]
}

// ---------------- maxpool 2x2 -> bf16, both layouts, LDS transpose --------
__global__ __launch_bounds__(256, 4)
void pool_kernel(const float* __restrict__ x, short* __restrict__ xph,
                 short* __restrict__ xpw){
  __shared__ short t_[128*LSP];     // [j][c]
  int bx = blockIdx.x;              // b*128 + i
  int b = bx >> 7, i = bx & 127;
  int tid = (int)threadIdx.x;
  int j  = tid & 127;               // lanes consecutive j -> coalesced reads
  int ch = tid >> 7;                // 2 channel planes per iter
  for (int rep = 0; rep < 64; ++rep){
    int c = rep*2 + ch;
    const float* p0 = x + (((b*128 + c)*256 + 2*i)*256 + 2*j);
    float2 a  = *(const float2*)p0;
    float2 bb = *(const float2*)(p0 + 256);
    t_[j*LSP + c] = f2bf(fmaxf(fmaxf(a.x, a.y), fmaxf(bb.x, bb.y)));
  }
  __syncthreads();
  // write both layouts from LDS
  int obase_h = ((b*128 + i)*128)*128;         // xph[b][i][j][c]
  for (int rep = 0; rep < 8; ++rep){
    int idx = rep*256 + tid;                   // 2048 v8s total
    int row = idx >> 4, seg = idx & 15;        // row=j, seg*8=c
    v8s v = *(const v8s*)(&t_[row*LSP + seg*8]);
    *(v8s*)(xph + obase_h + row*128 + seg*8) = v;
    *(v8s*)(xpw + ((b*128 + row)*128 + i)*128 + seg*8) = v;  // xpw[b][j][i][c]
  }
}

// ---------------- fused axial attention, merged dirs ----------------------
// 2048 blocks: dir = bx&1. One (b,s) per 512-thr block, 8 waves = 16-token
// bands. LDS: A = work buffer (x-tile products), WB = staged weight matrix
// cycled Wq -> Wk -> Wv -> Wout.
__global__ __launch_bounds__(512, 4)
void attn_kernel(const short* __restrict__ xp_hw, const short* __restrict__ xp_wh,
                 const short* __restrict__ wt,
                 const float* __restrict__ bout_h, const float* __restrict__ bout_w,
                 short* __restrict__ ah, short* __restrict__ aw){
  __shared__ short A[128*LSA];      // 34,816 B
  __shared__ short WB[128*LSA];     // 34,816 B

  const int bx = blockIdx.x;
  const int dir = bx & 1;
  const int sb = bx >> 1;
  const int b = sb >> 7, s = sb & 127;
  const int tid = (int)threadIdx.x;
  const int w = tid >> 6;
  const int lane = tid & 63;
  const int l15 = lane & 15, l4 = lane >> 4;

  const short* Wq   = wt + dir*65536;     // [oc][ic] 128x128 each
  const short* Wk   = Wq + 16384;
  const short* Wv   = Wq + 32768;
  const short* Wout = Wq + 49152;
  const float* bsrc = dir ? bout_w : bout_h;
  const short* xsrc = dir ? xp_hw : xp_wh;
  short*       ao   = dir ? aw : ah;

  // x A-frags: contiguous 32KB tile, 4 gather loads (lines fully used)
  const int xbase = ((b*128 + s)*128 + (16*w + l15))*128;
  v8s av[4];
  #pragma unroll
  for (int kk = 0; kk < 4; ++kk)
    av[kk] = *(const v8s*)(xsrc + xbase + kk*32 + l4*8);

  // stage macro: 128x128 bf16 matrix -> WB (stride LSA)
#define STAGE_W(SRC)                                                     \
  { _Pragma("unroll")                                                    \
    for (int r_ = 0; r_ < 4; ++r_){                                      \
      int idx_ = (r_*512 + tid) * 8;                                     \
      int oc_ = idx_ >> 7, ic_ = idx_ & 127;                             \
      *(v8s*)(&WB[oc_*LSA + ic_]) = *(const v8s*)((SRC) + idx_);         \
    } }

  STAGE_W(Wq);
  __syncthreads();                  // B1: Wq staged

  // ---- q = x @ Wq -> own band A [t][c]; read back as bq ----
  #pragma unroll
  for (int tc = 0; tc < 8; ++tc){
    v4f d = {0.f,0.f,0.f,0.f};
    #pragma unroll
    for (int kk = 0; kk < 4; ++kk){
      v8s bf = *(const v8s*)(&WB[(tc*16 + l15)*LSA + kk*32 + l4*8]);
      d = __builtin_amdgcn_mfma_f32_16x16x32_bf16(av[kk], bf, d, 0, 0, 0);
    }
    #pragma unroll
    for (int r = 0; r < 4; ++r)
      A[(16*w + 4*l4 + r)*LSA + 16*tc + l15] = f2bf(d[r]);
  }
  v8s bq[2][2];
  #pragma unroll
  for (int h = 0; h < 2; ++h)
    #pragma unroll
    for (int kk = 0; kk < 2; ++kk)
      bq[h][kk] = *(const v8s*)(&A[(16*w + l15)*LSA + h*64 + kk*32 + l4*8]);
  __syncthreads();                  // B2: Wq reads done

  STAGE_W(Wk);
  __syncthreads();                  // B3: Wk staged

  // ---- k = x @ Wk -> own band A [t][c] ----
  #pragma unroll
  for (int tc = 0; tc < 8; ++tc){
    v4f d = {0.f,0.f,0.f,0.f};
    #pragma unroll
    for (int kk = 0; kk < 4; ++kk){
      v8s bf = *(const v8s*)(&WB[(tc*16 + l15)*LSA + kk*32 + l4*8]);
      d = __builtin_amdgcn_mfma_f32_16x16x32_bf16(av[kk], bf, d, 0, 0, 0);
    }
    #pragma unroll
    for (int r = 0; r < 4; ++r)
      A[(16*w + 4*l4 + r)*LSA + 16*tc + l15] = f2bf(d[r]);
  }
  __syncthreads();                  // B4: k visible; Wk reads done

  STAGE_W(Wv);                      // overlap with S^T below

  // ---- S^T = K.Q^T per head + softmax; P packed in regs ----
  v4s pk[2][8];
  #pragma unroll
  for (int h = 0; h < 2; ++h){
    v4f st[8];
    #pragma unroll
    for (int jt = 0; jt < 8; ++jt){
      v4f d = {0.f,0.f,0.f,0.f};
      #pragma unroll
      for (int kk = 0; kk < 2; ++kk){
        v8s ak = *(const v8s*)(&A[(16*jt + l15)*LSA + h*64 + kk*32 + l4*8]);
        d = __builtin_amdgcn_mfma_f32_16x16x32_bf16(ak, bq[h][kk], d, 0, 0, 0);
      }
      st[jt] = d;
    }
    float mx = -1e30f;
    #pragma unroll
    for (int jt = 0; jt < 8; ++jt)
      #pragma unroll
      for (int r = 0; r < 4; ++r) mx = fmaxf(mx, st[jt][r]);
    mx = fmaxf(mx, __shfl_xor(mx, 16));
    mx = fmaxf(mx, __shfl_xor(mx, 32));
    float sm = 0.f;
    #pragma unroll
    for (int jt = 0; jt < 8; ++jt)
      #pragma unroll
      for (int r = 0; r < 4; ++r){
        float e = __expf((st[jt][r] - mx) * 0.125f);   // * dh^-0.5
        st[jt][r] = e; sm += e;
      }
    sm += __shfl_xor(sm, 16);
    sm += __shfl_xor(sm, 32);
    float inv = 1.0f / sm;
    #pragma unroll
    for (int jt = 0; jt < 8; ++jt)
      #pragma unroll
      for (int r = 0; r < 4; ++r) pk[h][jt][r] = f2bf(st[jt][r] * inv);
  }
  __syncthreads();                  // B5: k reads done (A free); Wv staged

  // ---- P -> own band A [i][j]; read back pa (per head, wave-local) ----
  v8s pa[2][4];
  #pragma unroll
  for (int h = 0; h < 2; ++h){
    #pragma unroll
    for (int jt = 0; jt < 8; ++jt)
      *(v4s*)(&A[(16*w + l15)*LSA + 16*jt + 4*l4]) = pk[h][jt];
    #pragma unroll
    for (int kk = 0; kk < 4; ++kk)
      pa[h][kk] = *(const v8s*)(&A[(16*w + l15)*LSA + kk*32 + l4*8]);
  }
  __syncthreads();                  // B6: all pa read-backs done

  // ---- v = x @ Wv -> v^T in A [ch][tok] (v4s along tok) ----
  #pragma unroll
  for (int tc = 0; tc < 8; ++tc){
    v4f d = {0.f,0.f,0.f,0.f};
    #pragma unroll
    for (int kk = 0; kk < 4; ++kk){
      v8s bf = *(const v8s*)(&WB[(tc*16 + l15)*LSA + kk*32 + l4*8]);
      d = __builtin_amdgcn_mfma_f32_16x16x32_bf16(av[kk], bf, d, 0, 0, 0);
    }
    v4s pkv;
    #pragma unroll
    for (int r = 0; r < 4; ++r) pkv[r] = f2bf(d[r]);
    *(v4s*)(&A[(16*tc + l15)*LSA + 16*w + 4*l4]) = pkv;
  }
  __syncthreads();                  // B7: v^T visible; Wv reads done

  STAGE_W(Wout);                    // overlap with O^T below

  // ---- O^T = V^T . P^T : A-frags from A(v^T), B = pa ----
  v4f ot[2][4];
  #pragma unroll
  for (int h = 0; h < 2; ++h)
    #pragma unroll
    for (int tc = 0; tc < 4; ++tc){
      v4f d = {0.f,0.f,0.f,0.f};
      #pragma unroll
      for (int kk = 0; kk < 4; ++kk){
        v8s vf = *(const v8s*)(&A[(64*h + 16*tc + l15)*LSA + kk*32 + l4*8]);
        d = __builtin_amdgcn_mfma_f32_16x16x32_bf16(vf, pa[h][kk], d, 0, 0, 0);
      }
      ot[h][tc] = d;
    }
  __syncthreads();                  // B8: v^T reads done; Wout staged

  // ---- O -> own band A [i][d]; ob; out-proj A=WB(Wout), B=ob; Z -> band --
  #pragma unroll
  for (int h = 0; h < 2; ++h)
    #pragma unroll
    for (int tc = 0; tc < 4; ++tc){
      v4s pko;
      #pragma unroll
      for (int r = 0; r < 4; ++r) pko[r] = f2bf(ot[h][tc][r]);
      *(v4s*)(&A[(16*w + l15)*LSA + 64*h + 16*tc + 4*l4]) = pko;
    }
  v8s ob[4];
  #pragma unroll
  for (int kk = 0; kk < 4; ++kk)
    ob[kk] = *(const v8s*)(&A[(16*w + l15)*LSA + kk*32 + l4*8]);
  #pragma unroll
  for (int tc = 0; tc < 8; ++tc){
    v4f d = {0.f,0.f,0.f,0.f};
    #pragma unroll
    for (int kk = 0; kk < 4; ++kk){
      v8s awf = *(const v8s*)(&WB[(tc*16 + l15)*LSA + kk*32 + l4*8]);
      d = __builtin_amdgcn_mfma_f32_16x16x32_bf16(awf, ob[kk], d, 0, 0, 0);
    }
    v4f bias = *(const v4f*)(bsrc + 16*tc + 4*l4);
    v4s z;
    #pragma unroll
    for (int r = 0; r < 4; ++r) z[r] = f2bf(d[r] + bias[r]);
    *(v4s*)(&A[(16*w + l15)*LSA + 16*tc + 4*l4]) = z;   // Z[i][oc], own band
  }
  __syncthreads();                  // B9: Z tile complete

  int obase = ((b*128 + s)*128)*128;
  #pragma unroll
  for (int r = 0; r < 4; ++r){
    int idx = (r*512 + tid) * 8;
    int t = idx >> 7, c = idx & 127;
    *(v8s*)(ao + obase + t*128 + c) = *(const v8s*)(&A[t*LSA + c]);
  }
#undef STAGE_W
}

// ---------------- concat + 1x1 conv + relu + bf16 y + stats ---------------
__global__ __launch_bounds__(512, 2)
void conv_kernel(const short* __restrict__ ah, const short* __restrict__ aw,
                 const short* __restrict__ xp, const short* __restrict__ wt,
                 short* __restrict__ yb, float* __restrict__ stats){
  __shared__ short cats[128*LSC];   // staged [t][256]; reused as y [256][132]
  __shared__ float lsum[256];
  __shared__ float lsq[256];
  const short* convT = wt + 131072; // [e][f] bf16
  int bx = blockIdx.x;              // b*128 + ii (image h-row; tokens j = w)
  int b = bx >> 7, ii = bx & 127;
  int tid = (int)threadIdx.x;
  int wv = tid >> 6, lane = tid & 63, l15 = lane & 15, l4 = lane >> 4;
  if (tid < 256){ lsum[tid] = 0.f; lsq[tid] = 0.f; }
  for (int r = 0; r < 4; ++r){
    int idx = (r*512 + tid) * 8;
    int t = idx >> 7, c = idx & 127;
    v8s hv = *(const v8s*)(ah + ((b*128 + t)*128 + ii)*128 + c);
    v8s wv_ = *(const v8s*)(aw + ((b*128 + ii)*128 + t)*128 + c);
    v8s o;
    #pragma unroll
    for (int k = 0; k < 8; ++k)
      o[k] = f2bf(fmaxf(bf2f(hv[k]) + bf2f(wv_[k]), 0.f));
    *(v8s*)(&cats[t*LSC + c]) = o;
    *(v8s*)(&cats[t*LSC + 128 + c]) =
        *(const v8s*)(xp + ((b*128 + ii)*128 + t)*128 + c);
  }
  __syncthreads();
  v8s af[8];
  #pragma unroll
  for (int kk = 0; kk < 8; ++kk)
    af[kk] = *(const v8s*)(&cats[(16*wv + l15)*LSC + kk*32 + l4*8]);
  __syncthreads();                  // all af loaded before y overwrites
  for (int tc = 0; tc < 16; ++tc){
    v4f d = {0.f,0.f,0.f,0.f};
    #pragma unroll
    for (int kk = 0; kk < 8; ++kk){
      v8s bf = *(const v8s*)(convT + (tc*16 + l15)*256 + kk*32 + l4*8);
      d = __builtin_amdgcn_mfma_f32_16x16x32_bf16(af[kk], bf, d, 0, 0, 0);
    }
    int e  = 16*tc + l15;
    int j0 = 16*wv + 4*l4;
    v4s yp;
    float s1 = 0.f, s2 = 0.f;
    #pragma unroll
    for (int r = 0; r < 4; ++r){
      float y = fmaxf(d[r], 0.f);
      yp[r] = f2bf(y);
      s1 += y; s2 += y*y;
    }
    *(v4s*)(&cats[e*132 + j0]) = yp;
    s1 += __shfl_xor(s1, 16); s1 += __shfl_xor(s1, 32);
    s2 += __shfl_xor(s2, 16); s2 += __shfl_xor(s2, 32);
    if (l4 == 0){
      atomicAdd(&lsum[e], s1);
      atomicAdd(&lsq[e], s2);
    }
  }
  __syncthreads();
  for (int r = 0; r < 8; ++r){      // coalesced bf16 y store [b][e][ii][j]
    int idx = (r*512 + tid) * 8;
    int e = idx >> 7, j = idx & 127;
    *(v8s*)(yb + ((b*256 + e)*128 + ii)*128 + j) = *(const v8s*)(&cats[e*132 + j]);
  }
  if (tid < 256){
    int c = bx & 15;                // 16-way spread
    atomicAdd(&stats[c*512 + tid],       lsum[tid]);
    atomicAdd(&stats[c*512 + 256 + tid], lsq[tid]);
  }
}

// ---------------- BN: bf16 y -> fp32 out, block = one (b,e) plane ---------
__global__ void bn_kernel(const short* __restrict__ yb, float* __restrict__ out,
                          const float* __restrict__ stats,
                          const float* __restrict__ gamma, const float* __restrict__ beta){
  const float invn = 1.0f / 131072.0f;
  int bx = blockIdx.x;              // b*256 + e
  int e = bx & 255;
  float s1 = 0.f, s2 = 0.f;
  #pragma unroll
  for (int c = 0; c < 16; ++c){
    s1 += stats[c*512 + e];
    s2 += stats[c*512 + 256 + e];
  }
  float m   = s1 * invn;
  float var = s2 * invn - m * m;
  float sc  = gamma[e] * rsqrtf(var + 1e-5f);
  float sh  = beta[e] - m * sc;
  int base = bx * 16384;
  int tid = (int)threadIdx.x;       // 256
  for (int rep = 0; rep < 8; ++rep){
    int idx = base + (rep*256 + tid)*8;
    v8s yv = *(const v8s*)(yb + idx);
    v4f o1, o2;
    #pragma unroll
    for (int r = 0; r < 4; ++r){
      o1[r] = bf2f(yv[r])   * sc + sh;
      o2[r] = bf2f(yv[4+r]) * sc + sh;
    }
    *(v4f*)(out + idx)     = o1;
    *(v4f*)(out + idx + 4) = o2;
  }
}

extern "C" void kernel_launch(void* const* d_in, const int* in_sizes, int n_in,
                              void* d_out, int out_size, void* d_ws, size_t ws_size,
                              hipStream_t stream){
  const float* x      = (const float*)d_in[0];
  const float* Wq_h   = (const float*)d_in[1];
  const float* Wkv_h  = (const float*)d_in[2];
  const float* Wout_h = (const float*)d_in[3];
  const float* bout_h = (const float*)d_in[4];
  const float* Wq_w   = (const float*)d_in[5];
  const float* Wkv_w  = (const float*)d_in[6];
  const float* Wout_w = (const float*)d_in[7];
  const float* bout_w = (const float*)d_in[8];
  const float* conv_w = (const float*)d_in[9];
  const float* gamma  = (const float*)d_in[10];
  const float* beta   = (const float*)d_in[11];
  float* out = (float*)d_out;

  char* ws = (char*)d_ws;
  short* xp_hw = (short*)(ws);               // 33,554,432 B  [b][h][w][c]
  short* xp_wh = (short*)(ws +  33554432);   // 33,554,432 B  [b][w][h][c]
  short* ah    = (short*)(ws +  67108864);   // 33,554,432 B  [b][w][h][c]
  short* aw    = (short*)(ws + 100663296);   // 33,554,432 B  [b][h][w][c]
  short* yb    = (short*)(ws + 134217728);   // 67,108,864 B  [b][e][h][w]
  short* wt    = (short*)(ws + 201326592);   //    393,216 B
  float* stats = (float*)(ws + 201719808);   //     32,768 B

  prep_kernel<<<768, 256, 0, stream>>>(Wq_h, Wkv_h, Wout_h, Wq_w, Wkv_w, Wout_w,
                                       conv_w, wt, stats);
  pool_kernel<<<1024, 256, 0, stream>>>(x, xp_hw, xp_wh);
  attn_kernel<<<2048, 512, 0, stream>>>(xp_hw, xp_wh, wt, bout_h, bout_w, ah, aw);
  conv_kernel<<<1024, 512, 0, stream>>>(ah, aw, xp_hw, wt, yb, stats);
  bn_kernel<<<2048, 256, 0, stream>>>(yb, out, stats, gamma, beta);
}

// Round 5
// 283.366 us; speedup vs baseline: 1.8588x; 1.2179x over previous
//
#include <hip/hip_runtime.h>

// BlockAxialDown: pool2x2 -> axial attn (H)+(W) -> relu -> concat -> 1x1 conv
// -> relu -> batch-stat BN -> NCHW.  B=8 C=128 H2=W2=128 E=256, heads=2 dh=64.
//
// ws (bf16):
//   xp_hw [b][h][w][c], xp_wh [b][w][h][c]  pooled x, both layouts
//   ah [b][w][h][c]  H-attn out (+bias)
//   aw [b][h][w][c]  W-attn out (+bias)
//   yb [b][e][h][w]  pre-BN conv out
// attn: weights reg-prefetched at t0, staged to LDS just-in-time.
// conv: wave owns 2 e-tiles, weight frags in regs reused over 8 token-tiles.

typedef short v8s __attribute__((ext_vector_type(8)));
typedef short v4s __attribute__((ext_vector_type(4)));
typedef float v4f __attribute__((ext_vector_type(4)));

#define LSA 136   // attn LDS row stride (bf16)
#define LSC 264   // conv LDS row stride
#define LSP 130   // pool LDS row stride

static __device__ __forceinline__ short f2bf(float f){
  unsigned u = __builtin_bit_cast(unsigned, f);
  u = (u + 0x7FFFu + ((u >> 16) & 1u)) >> 16;   // RNE
  return (short)u;
}
static __device__ __forceinline__ float bf2f(short s){
  unsigned u = ((unsigned)(unsigned short)s) << 16;
  return __builtin_bit_cast(float, u);
}

// ---------------- prep: transpose weights to bf16 [out][in]; zero stats ----
__global__ void prep_kernel(const float* __restrict__ Wq_h, const float* __restrict__ Wkv_h,
                            const float* __restrict__ Wout_h, const float* __restrict__ Wq_w,
                            const float* __restrict__ Wkv_w, const float* __restrict__ Wout_w,
                            const float* __restrict__ conv_w, short* __restrict__ wt,
                            float* __restrict__ stats){
  int idx = blockIdx.x * 256 + threadIdx.x;   // 768*256 = 196608 exactly
  if (idx < 8192) stats[idx] = 0.0f;          // 16 copies x 512
  const float* src; int K, O, base;
  if      (idx <  16384){ base = 0;      K=128; O=128; src=Wq_h;  }
  else if (idx <  49152){ base = 16384;  K=128; O=256; src=Wkv_h; }
  else if (idx <  65536){ base = 49152;  K=128; O=128; src=Wout_h;}
  else if (idx <  81920){ base = 65536;  K=128; O=128; src=Wq_w;  }
  else if (idx < 114688){ base = 81920;  K=128; O=256; src=Wkv_w; }
  else if (idx < 131072){ base = 114688; K=128; O=128; src=Wout_w;}
  else                  { base = 131072; K=256; O=256; src=conv_w;}
  int local = idx - base;
  int o = local / K, i = local - o * K;
  wt[idx] = f2bf(src[i * O + o]);   // dst[o][i] = src[i][o]
}

// ---------------- maxpool 2x2 -> bf16, both layouts, LDS transpose --------
__global__ __launch_bounds__(256, 4)
void pool_kernel(const float* __restrict__ x, short* __restrict__ xph,
                 short* __restrict__ xpw){
  __shared__ short t_[128*LSP];     // [j][c]
  int bx = blockIdx.x;              // b*128 + i
  int b = bx >> 7, i = bx & 127;
  int tid = (int)threadIdx.x;
  int j  = tid & 127;               // lanes consecutive j -> coalesced reads
  int ch = tid >> 7;                // 2 channel planes per iter
  for (int rep = 0; rep < 64; ++rep){
    int c = rep*2 + ch;
    const float* p0 = x + (((b*128 + c)*256 + 2*i)*256 + 2*j);
    float2 a  = *(const float2*)p0;
    float2 bb = *(const float2*)(p0 + 256);
    t_[j*LSP + c] = f2bf(fmaxf(fmaxf(a.x, a.y), fmaxf(bb.x, bb.y)));
  }
  __syncthreads();
  int obase_h = ((b*128 + i)*128)*128;         // xph[b][i][j][c]
  for (int rep = 0; rep < 8; ++rep){
    int idx = rep*256 + tid;                   // 2048 v8s total
    int row = idx >> 4, seg = idx & 15;        // row=j, seg*8=c
    v8s v = *(const v8s*)(&t_[row*LSP + seg*8]);
    *(v8s*)(xph + obase_h + row*128 + seg*8) = v;
    *(v8s*)(xpw + ((b*128 + row)*128 + i)*128 + seg*8) = v;  // xpw[b][j][i][c]
  }
}

// ---------------- fused axial attention, merged dirs ----------------------
// 2048 blocks: dir = bx&1. One (b,s) per 512-thr block, 8 waves = 16-token
// bands. All four weight matrices reg-prefetched at t0; WB staged just-in-time.
__global__ __launch_bounds__(512, 2)
void attn_kernel(const short* __restrict__ xp_hw, const short* __restrict__ xp_wh,
                 const short* __restrict__ wt,
                 const float* __restrict__ bout_h, const float* __restrict__ bout_w,
                 short* __restrict__ ah, short* __restrict__ aw){
  __shared__ short A[128*LSA];      // 34,816 B
  __shared__ short WB[128*LSA];     // 34,816 B

  const int bx = blockIdx.x;
  const int dir = bx & 1;
  const int sb = bx >> 1;
  const int b = sb >> 7, s = sb & 127;
  const int tid = (int)threadIdx.x;
  const int w = tid >> 6;
  const int lane = tid & 63;
  const int l15 = lane & 15, l4 = lane >> 4;

  const short* Wq   = wt + dir*65536;     // [oc][ic] 128x128 each
  const short* Wk   = Wq + 16384;
  const short* Wv   = Wq + 32768;
  const short* Wout = Wq + 49152;
  const float* bsrc = dir ? bout_w : bout_h;
  const short* xsrc = dir ? xp_hw : xp_wh;
  short*       ao   = dir ? aw : ah;

  // ---- issue ALL global loads up front (latency hidden under phases) ----
  const int xbase = ((b*128 + s)*128 + (16*w + l15))*128;
  v8s av[4];
  #pragma unroll
  for (int kk = 0; kk < 4; ++kk)
    av[kk] = *(const v8s*)(xsrc + xbase + kk*32 + l4*8);
  v8s wq_r[4], wk_r[4], wv_r[4], wo_r[4];
  #pragma unroll
  for (int r = 0; r < 4; ++r){
    int idx = (r*512 + tid) * 8;
    wq_r[r] = *(const v8s*)(Wq   + idx);
    wk_r[r] = *(const v8s*)(Wk   + idx);
    wv_r[r] = *(const v8s*)(Wv   + idx);
    wo_r[r] = *(const v8s*)(Wout + idx);
  }

#define STAGE_R(RG)                                                      \
  { _Pragma("unroll")                                                    \
    for (int r_ = 0; r_ < 4; ++r_){                                      \
      int idx_ = (r_*512 + tid) * 8;                                     \
      int oc_ = idx_ >> 7, ic_ = idx_ & 127;                             \
      *(v8s*)(&WB[oc_*LSA + ic_]) = RG[r_];                              \
    } }

  STAGE_R(wq_r);
  __syncthreads();                  // B1: Wq staged

  // ---- q = x @ Wq -> own band A [t][c]; read back as bq ----
  #pragma unroll
  for (int tc = 0; tc < 8; ++tc){
    v4f d = {0.f,0.f,0.f,0.f};
    #pragma unroll
    for (int kk = 0; kk < 4; ++kk){
      v8s bf = *(const v8s*)(&WB[(tc*16 + l15)*LSA + kk*32 + l4*8]);
      d = __builtin_amdgcn_mfma_f32_16x16x32_bf16(av[kk], bf, d, 0, 0, 0);
    }
    #pragma unroll
    for (int r = 0; r < 4; ++r)
      A[(16*w + 4*l4 + r)*LSA + 16*tc + l15] = f2bf(d[r]);
  }
  v8s bq[2][2];
  #pragma unroll
  for (int h = 0; h < 2; ++h)
    #pragma unroll
    for (int kk = 0; kk < 2; ++kk)
      bq[h][kk] = *(const v8s*)(&A[(16*w + l15)*LSA + h*64 + kk*32 + l4*8]);
  __syncthreads();                  // B2: Wq reads done

  STAGE_R(wk_r);
  __syncthreads();                  // B3: Wk staged

  // ---- k = x @ Wk -> own band A [t][c] ----
  #pragma unroll
  for (int tc = 0; tc < 8; ++tc){
    v4f d = {0.f,0.f,0.f,0.f};
    #pragma unroll
    for (int kk = 0; kk < 4; ++kk){
      v8s bf = *(const v8s*)(&WB[(tc*16 + l15)*LSA + kk*32 + l4*8]);
      d = __builtin_amdgcn_mfma_f32_16x16x32_bf16(av[kk], bf, d, 0, 0, 0);
    }
    #pragma unroll
    for (int r = 0; r < 4; ++r)
      A[(16*w + 4*l4 + r)*LSA + 16*tc + l15] = f2bf(d[r]);
  }
  __syncthreads();                  // B4: k visible; Wk reads done

  STAGE_R(wv_r);                    // ds_writes overlap S^T below

  // ---- S^T = K.Q^T per head + softmax; P packed in regs ----
  v4s pk[2][8];
  #pragma unroll
  for (int h = 0; h < 2; ++h){
    v4f st[8];
    #pragma unroll
    for (int jt = 0; jt < 8; ++jt){
      v4f d = {0.f,0.f,0.f,0.f};
      #pragma unroll
      for (int kk = 0; kk < 2; ++kk){
        v8s ak = *(const v8s*)(&A[(16*jt + l15)*LSA + h*64 + kk*32 + l4*8]);
        d = __builtin_amdgcn_mfma_f32_16x16x32_bf16(ak, bq[h][kk], d, 0, 0, 0);
      }
      st[jt] = d;
    }
    float mx = -1e30f;
    #pragma unroll
    for (int jt = 0; jt < 8; ++jt)
      #pragma unroll
      for (int r = 0; r < 4; ++r) mx = fmaxf(mx, st[jt][r]);
    mx = fmaxf(mx, __shfl_xor(mx, 16));
    mx = fmaxf(mx, __shfl_xor(mx, 32));
    float sm = 0.f;
    #pragma unroll
    for (int jt = 0; jt < 8; ++jt)
      #pragma unroll
      for (int r = 0; r < 4; ++r){
        float e = __expf((st[jt][r] - mx) * 0.125f);   // * dh^-0.5
        st[jt][r] = e; sm += e;
      }
    sm += __shfl_xor(sm, 16);
    sm += __shfl_xor(sm, 32);
    float inv = 1.0f / sm;
    #pragma unroll
    for (int jt = 0; jt < 8; ++jt)
      #pragma unroll
      for (int r = 0; r < 4; ++r) pk[h][jt][r] = f2bf(st[jt][r] * inv);
  }
  __syncthreads();                  // B5: k reads done (A free); Wv staged

  // ---- P -> own band A [i][j]; read back pa (per head, wave-local) ----
  v8s pa[2][4];
  #pragma unroll
  for (int h = 0; h < 2; ++h){
    #pragma unroll
    for (int jt = 0; jt < 8; ++jt)
      *(v4s*)(&A[(16*w + l15)*LSA + 16*jt + 4*l4]) = pk[h][jt];
    #pragma unroll
    for (int kk = 0; kk < 4; ++kk)
      pa[h][kk] = *(const v8s*)(&A[(16*w + l15)*LSA + kk*32 + l4*8]);
  }
  __syncthreads();                  // B6: all pa read-backs done

  // ---- v = x @ Wv -> v^T in A [ch][tok] ----
  #pragma unroll
  for (int tc = 0; tc < 8; ++tc){
    v4f d = {0.f,0.f,0.f,0.f};
    #pragma unroll
    for (int kk = 0; kk < 4; ++kk){
      v8s bf = *(const v8s*)(&WB[(tc*16 + l15)*LSA + kk*32 + l4*8]);
      d = __builtin_amdgcn_mfma_f32_16x16x32_bf16(av[kk], bf, d, 0, 0, 0);
    }
    v4s pkv;
    #pragma unroll
    for (int r = 0; r < 4; ++r) pkv[r] = f2bf(d[r]);
    *(v4s*)(&A[(16*tc + l15)*LSA + 16*w + 4*l4]) = pkv;
  }
  __syncthreads();                  // B7: v^T visible; Wv reads done

  STAGE_R(wo_r);                    // overlap with O^T below

  // ---- O^T = V^T . P^T : A-frags from A(v^T), B = pa ----
  v4f ot[2][4];
  #pragma unroll
  for (int h = 0; h < 2; ++h)
    #pragma unroll
    for (int tc = 0; tc < 4; ++tc){
      v4f d = {0.f,0.f,0.f,0.f};
      #pragma unroll
      for (int kk = 0; kk < 4; ++kk){
        v8s vf = *(const v8s*)(&A[(64*h + 16*tc + l15)*LSA + kk*32 + l4*8]);
        d = __builtin_amdgcn_mfma_f32_16x16x32_bf16(vf, pa[h][kk], d, 0, 0, 0);
      }
      ot[h][tc] = d;
    }
  __syncthreads();                  // B8: v^T reads done; Wout staged

  // ---- O -> own band A [i][d]; ob; out-proj; Z -> own band ----
  #pragma unroll
  for (int h = 0; h < 2; ++h)
    #pragma unroll
    for (int tc = 0; tc < 4; ++tc){
      v4s pko;
      #pragma unroll
      for (int r = 0; r < 4; ++r) pko[r] = f2bf(ot[h][tc][r]);
      *(v4s*)(&A[(16*w + l15)*LSA + 64*h + 16*tc + 4*l4]) = pko;
    }
  v8s ob[4];
  #pragma unroll
  for (int kk = 0; kk < 4; ++kk)
    ob[kk] = *(const v8s*)(&A[(16*w + l15)*LSA + kk*32 + l4*8]);
  #pragma unroll
  for (int tc = 0; tc < 8; ++tc){
    v4f d = {0.f,0.f,0.f,0.f};
    #pragma unroll
    for (int kk = 0; kk < 4; ++kk){
      v8s awf = *(const v8s*)(&WB[(tc*16 + l15)*LSA + kk*32 + l4*8]);
      d = __builtin_amdgcn_mfma_f32_16x16x32_bf16(awf, ob[kk], d, 0, 0, 0);
    }
    v4f bias = *(const v4f*)(bsrc + 16*tc + 4*l4);
    v4s z;
    #pragma unroll
    for (int r = 0; r < 4; ++r) z[r] = f2bf(d[r] + bias[r]);
    *(v4s*)(&A[(16*w + l15)*LSA + 16*tc + 4*l4]) = z;   // Z[i][oc], own band
  }
  __syncthreads();                  // B9: Z tile complete

  int obase = ((b*128 + s)*128)*128;
  #pragma unroll
  for (int r = 0; r < 4; ++r){
    int idx = (r*512 + tid) * 8;
    int t = idx >> 7, c = idx & 127;
    *(v8s*)(ao + obase + t*128 + c) = *(const v8s*)(&A[t*LSA + c]);
  }
#undef STAGE_R
}

// ---------------- concat + 1x1 conv + relu + bf16 y + stats ---------------
// Wave owns e-tiles {wv, wv+8}; weight frags in regs (16 global loads, 8x
// reuse over token-tiles). y accumulated in regs, one LDS transpose at end.
__global__ __launch_bounds__(512, 2)
void conv_kernel(const short* __restrict__ ah, const short* __restrict__ aw,
                 const short* __restrict__ xp, const short* __restrict__ wt,
                 short* __restrict__ yb, float* __restrict__ stats){
  __shared__ short cats[128*LSC];   // staged [t][256]; reused as y [256][132]
  __shared__ float lsum[256];
  __shared__ float lsq[256];
  const short* convT = wt + 131072; // [e][f] bf16
  int bx = blockIdx.x;              // b*128 + ii (image h-row; tokens j = w)
  int b = bx >> 7, ii = bx & 127;
  int tid = (int)threadIdx.x;
  int wv = tid >> 6, lane = tid & 63, l15 = lane & 15, l4 = lane >> 4;
  if (tid < 256){ lsum[tid] = 0.f; lsq[tid] = 0.f; }

  // weight frags for this wave's two e-tiles (issued first, reused 8x)
  v8s wf[2][8];
  #pragma unroll
  for (int x = 0; x < 2; ++x)
    #pragma unroll
    for (int kk = 0; kk < 8; ++kk)
      wf[x][kk] = *(const v8s*)(convT + (((wv + 8*x)*16 + l15)*256) + kk*32 + l4*8);

  // stage cat = [relu(ah+aw) | xp]
  for (int r = 0; r < 4; ++r){
    int idx = (r*512 + tid) * 8;
    int t = idx >> 7, c = idx & 127;
    v8s hv = *(const v8s*)(ah + ((b*128 + t)*128 + ii)*128 + c);
    v8s wv_ = *(const v8s*)(aw + ((b*128 + ii)*128 + t)*128 + c);
    v8s o;
    #pragma unroll
    for (int k = 0; k < 8; ++k)
      o[k] = f2bf(fmaxf(bf2f(hv[k]) + bf2f(wv_[k]), 0.f));
    *(v8s*)(&cats[t*LSC + c]) = o;
    *(v8s*)(&cats[t*LSC + 128 + c]) =
        *(const v8s*)(xp + ((b*128 + ii)*128 + t)*128 + c);
  }
  __syncthreads();

  v4s ypk[2][8];                    // packed y tiles [x][tt]
  float s1[2] = {0.f,0.f}, s2[2] = {0.f,0.f};
  #pragma unroll
  for (int tt = 0; tt < 8; ++tt){
    v4f d0 = {0.f,0.f,0.f,0.f}, d1 = {0.f,0.f,0.f,0.f};
    #pragma unroll
    for (int kk = 0; kk < 8; ++kk){
      v8s af = *(const v8s*)(&cats[(16*tt + l15)*LSC + kk*32 + l4*8]);
      d0 = __builtin_amdgcn_mfma_f32_16x16x32_bf16(af, wf[0][kk], d0, 0, 0, 0);
      d1 = __builtin_amdgcn_mfma_f32_16x16x32_bf16(af, wf[1][kk], d1, 0, 0, 0);
    }
    #pragma unroll
    for (int r = 0; r < 4; ++r){
      float y0 = fmaxf(d0[r], 0.f), y1 = fmaxf(d1[r], 0.f);
      ypk[0][tt][r] = f2bf(y0); ypk[1][tt][r] = f2bf(y1);
      s1[0] += y0; s2[0] += y0*y0;
      s1[1] += y1; s2[1] += y1*y1;
    }
  }
  // per-e stats: reduce across l4 groups (token coverage -> all 128)
  #pragma unroll
  for (int x = 0; x < 2; ++x){
    s1[x] += __shfl_xor(s1[x], 16); s1[x] += __shfl_xor(s1[x], 32);
    s2[x] += __shfl_xor(s2[x], 16); s2[x] += __shfl_xor(s2[x], 32);
  }
  if (l4 == 0){
    #pragma unroll
    for (int x = 0; x < 2; ++x){
      int e = (wv + 8*x)*16 + l15;
      atomicAdd(&lsum[e], s1[x]);
      atomicAdd(&lsq[e],  s2[x]);
    }
  }
  __syncthreads();                  // all cat reads done; reuse as y [256][132]
  #pragma unroll
  for (int x = 0; x < 2; ++x)
    #pragma unroll
    for (int tt = 0; tt < 8; ++tt)
      *(v4s*)(&cats[((wv + 8*x)*16 + l15)*132 + 16*tt + 4*l4]) = ypk[x][tt];
  __syncthreads();
  for (int r = 0; r < 8; ++r){      // coalesced bf16 y store [b][e][ii][j]
    int idx = (r*512 + tid) * 8;
    int e = idx >> 7, j = idx & 127;
    *(v8s*)(yb + ((b*256 + e)*128 + ii)*128 + j) = *(const v8s*)(&cats[e*132 + j]);
  }
  if (tid < 256){
    int c = bx & 15;                // 16-way spread
    atomicAdd(&stats[c*512 + tid],       lsum[tid]);
    atomicAdd(&stats[c*512 + 256 + tid], lsq[tid]);
  }
}

// ---------------- BN: bf16 y -> fp32 out, block = one (b,e) plane ---------
__global__ void bn_kernel(const short* __restrict__ yb, float* __restrict__ out,
                          const float* __restrict__ stats,
                          const float* __restrict__ gamma, const float* __restrict__ beta){
  const float invn = 1.0f / 131072.0f;
  int bx = blockIdx.x;              // b*256 + e
  int e = bx & 255;
  float s1 = 0.f, s2 = 0.f;
  #pragma unroll
  for (int c = 0; c < 16; ++c){
    s1 += stats[c*512 + e];
    s2 += stats[c*512 + 256 + e];
  }
  float m   = s1 * invn;
  float var = s2 * invn - m * m;
  float sc  = gamma[e] * rsqrtf(var + 1e-5f);
  float sh  = beta[e] - m * sc;
  int base = bx * 16384;
  int tid = (int)threadIdx.x;       // 256
  for (int rep = 0; rep < 8; ++rep){
    int idx = base + (rep*256 + tid)*8;
    v8s yv = *(const v8s*)(yb + idx);
    v4f o1, o2;
    #pragma unroll
    for (int r = 0; r < 4; ++r){
      o1[r] = bf2f(yv[r])   * sc + sh;
      o2[r] = bf2f(yv[4+r]) * sc + sh;
    }
    *(v4f*)(out + idx)     = o1;
    *(v4f*)(out + idx + 4) = o2;
  }
}

extern "C" void kernel_launch(void* const* d_in, const int* in_sizes, int n_in,
                              void* d_out, int out_size, void* d_ws, size_t ws_size,
                              hipStream_t stream){
  const float* x      = (const float*)d_in[0];
  const float* Wq_h   = (const float*)d_in[1];
  const float* Wkv_h  = (const float*)d_in[2];
  const float* Wout_h = (const float*)d_in[3];
  const float* bout_h = (const float*)d_in[4];
  const float* Wq_w   = (const float*)d_in[5];
  const float* Wkv_w  = (const float*)d_in[6];
  const float* Wout_w = (const float*)d_in[7];
  const float* bout_w = (const float*)d_in[8];
  const float* conv_w = (const float*)d_in[9];
  const float* gamma  = (const float*)d_in[10];
  const float* beta   = (const float*)d_in[11];
  float* out = (float*)d_out;

  char* ws = (char*)d_ws;
  short* xp_hw = (short*)(ws);               // 33,554,432 B  [b][h][w][c]
  short* xp_wh = (short*)(ws +  33554432);   // 33,554,432 B  [b][w][h][c]
  short* ah    = (short*)(ws +  67108864);   // 33,554,432 B  [b][w][h][c]
  short* aw    = (short*)(ws + 100663296);   // 33,554,432 B  [b][h][w][c]
  short* yb    = (short*)(ws + 134217728);   // 67,108,864 B  [b][e][h][w]
  short* wt    = (short*)(ws + 201326592);   //    393,216 B
  float* stats = (float*)(ws + 201719808);   //     32,768 B

  prep_kernel<<<768, 256, 0, stream>>>(Wq_h, Wkv_h, Wout_h, Wq_w, Wkv_w, Wout_w,
                                       conv_w, wt, stats);
  pool_kernel<<<1024, 256, 0, stream>>>(x, xp_hw, xp_wh);
  attn_kernel<<<2048, 512, 0, stream>>>(xp_hw, xp_wh, wt, bout_h, bout_w, ah, aw);
  conv_kernel<<<1024, 512, 0, stream>>>(ah, aw, xp_hw, wt, yb, stats);
  bn_kernel<<<2048, 256, 0, stream>>>(yb, out, stats, gamma, beta);
}